// Round 6
// baseline (443.335 us; speedup 1.0000x reference)
//
#include <hip/hip_runtime.h>
#include <math.h>
#include <stdint.h>

#define Bb   128
#define Nn   100
#define Ee   3200
#define NTOT (Bb*Nn)    // 12800
#define ETOT (Bb*Ee)    // 409600
#define CAP  768        // LDS edge capacity per k_mlpz chunk

// XCD swizzle: blockIdx&7 -> XCD (dispatch round-robin over 8 XCDs).
// XCD x owns batches [16x,16x+16): producers and consumers of a batch's
// data land on the same XCD -> L2-resident intermediates. Perf-only.
// R5 lesson: do NOT fuse to one-block-per-batch — 128 blocks = 8% occupancy,
// latency-bound phases with nothing to hide behind (313us vs this split's ~120).

// ---------------- K_csr: per-batch CSR build + mark, all-LDS ----------------

__global__ __launch_bounds__(256) void k_csr(const int* __restrict__ ei,
                                             const int* __restrict__ agent,
                                             int* __restrict__ off,
                                             int2* __restrict__ cpair,
                                             int* __restrict__ mark)
{
    int b = ((blockIdx.x & 7) << 4) + (blockIdx.x >> 3);
    int t = threadIdx.x;
    __shared__ int cnt[128];
    __shared__ int exc[128];
    __shared__ int cur[128];
    if (t < 128) cnt[t] = 0;
    if (t < Nn) mark[b * Nn + t] = 0;
    __syncthreads();
    const int* eis = ei + (size_t)b * 2 * Ee;       // src row
    const int* eid = eis + Ee;                      // dst row
    for (int e = t; e < Ee; e += 256) atomicAdd(&cnt[eid[e]], 1);
    __syncthreads();
    if (t < 128) exc[t] = cnt[t];
    __syncthreads();
    for (int d = 1; d < 128; d <<= 1) {
        int v = 0;
        if (t < 128 && t >= d) v = exc[t - d];
        __syncthreads();
        if (t < 128) exc[t] += v;
        __syncthreads();
    }
    if (t < 128) { int e0 = exc[t] - cnt[t]; exc[t] = e0; cur[t] = e0; }  // exclusive
    __syncthreads();
    if (t < Nn) off[b * Nn + t] = b * Ee + exc[t];
    if (b == Bb - 1 && t == 0) off[NTOT] = ETOT;
    int an = agent[b];
    for (int e = t; e < Ee; e += 256) {
        int dst = eid[e];
        int idx = atomicAdd(&cur[dst], 1);
        cpair[(size_t)b * Ee + idx] = make_int2(eis[e] + b * Nn, b * Ee + e);
        if (dst == an) mark[b * Nn + eis[e]] = 1;
    }
    if (t == 0) mark[b * Nn + an] = 1;
}

// ---------------- K_mlpz: edge-parallel MLP + segmented node-sum + q/k/v ----------------
// 512 threads, 16 nodes/block; CSR edge lists of 16 consecutive nodes are
// contiguous -> MLP runs edge-parallel at ~100% lane utilization.

__device__ __forceinline__ void ln_reg(float* h, const float* __restrict__ g,
                                       const float* __restrict__ b) {
    float s = 0.f;
#pragma unroll
    for (int c = 0; c < 16; c++) s += h[c];
    float m = s * 0.0625f;
    float v = 0.f;
#pragma unroll
    for (int c = 0; c < 16; c++) { float d = h[c] - m; v += d * d; }
    float r = rsqrtf(v * 0.0625f + 1e-5f);
#pragma unroll
    for (int c = 0; c < 16; c++) h[c] = (h[c] - m) * r * g[c] + b[c];
}

__global__ __launch_bounds__(512) void k_mlpz(
    const float* __restrict__ nf, const float* __restrict__ ea, const float* __restrict__ ee,
    const float* __restrict__ W1, const float* __restrict__ b1,
    const float* __restrict__ W2, const float* __restrict__ b2,
    const float* __restrict__ W3, const float* __restrict__ b3,
    const float* __restrict__ lg, const float* __restrict__ lb,
    const float* __restrict__ Wq, const float* __restrict__ bq,
    const float* __restrict__ Wk, const float* __restrict__ bk,
    const float* __restrict__ Wv, const float* __restrict__ bv,
    const int* __restrict__ off, const int2* __restrict__ cpair,
    float* __restrict__ z, float* __restrict__ q1, float* __restrict__ k1, float* __restrict__ v1)
{
    __shared__ float hls[CAP][17];    // stride 17: conflict-free scalar access
    __shared__ int soff[17];
    int t = threadIdx.x;
    int lane = t & 63;
    int w = t >> 6;                   // 8 waves
    int blk = (blockIdx.x & 7) * 100 + (blockIdx.x >> 3);   // 800 blocks
    int n0 = blk * 16;

    if (t < 17) soff[t] = off[n0 + t];
    __syncthreads();
    int e0 = soff[0], e1 = soff[16];

    // two nodes per wave
    int nA = 2 * w, nB = 2 * w + 1;   // local node ids
    int c = lane & 15, slot = lane >> 4;
    float zpA = 0.f, zpB = 0.f;

    for (int cs = e0; cs < e1; cs += CAP) {
        int m = min(CAP, e1 - cs);
        // ---- edge-parallel MLP into LDS ----
        for (int i = t; i < m; i += 512) {
            int2 p = cpair[cs + i];
            int et = (int)nf[p.x];
            float in[12];
#pragma unroll
            for (int j = 0; j < 4; j++) in[j] = ee[et * 4 + j];
            const float4* ea4 = (const float4*)(ea + (size_t)p.y * 8);
            float4 ua = ea4[0], ub = ea4[1];
            in[4] = ua.x; in[5] = ua.y; in[6] = ua.z; in[7] = ua.w;
            in[8] = ub.x; in[9] = ub.y; in[10] = ub.z; in[11] = ub.w;

            float h1[16];
#pragma unroll
            for (int cc = 0; cc < 16; cc++) {
                float s = b1[cc];
#pragma unroll
                for (int j = 0; j < 12; j++) s = fmaf(W1[cc * 12 + j], in[j], s);
                h1[cc] = fmaxf(s, 0.f);
            }
            ln_reg(h1, lg, lb);
            float h2[16];
#pragma unroll
            for (int cc = 0; cc < 16; cc++) {
                float s = b2[cc];
#pragma unroll
                for (int j = 0; j < 16; j++) s = fmaf(W2[cc * 16 + j], h1[j], s);
                h2[cc] = fmaxf(s, 0.f);
            }
            ln_reg(h2, lg, lb);
            float h3[16];
#pragma unroll
            for (int cc = 0; cc < 16; cc++) {
                float s = b3[cc];
#pragma unroll
                for (int j = 0; j < 16; j++) s = fmaf(W3[cc * 16 + j], h2[j], s);
                h3[cc] = fmaxf(s, 0.f);
            }
            ln_reg(h3, lg, lb);
#pragma unroll
            for (int cc = 0; cc < 16; cc++) hls[i][cc] = h3[cc];
        }
        __syncthreads();
        // ---- segmented reduction: wave w sums its two nodes' rows ----
        {
            int rloA = max(soff[nA], cs) - cs, rhiA = min(soff[nA + 1], cs + m) - cs;
            for (int r = rloA + slot; r < rhiA; r += 4) zpA += hls[r][c];
            int rloB = max(soff[nB], cs) - cs, rhiB = min(soff[nB + 1], cs + m) - cs;
            for (int r = rloB + slot; r < rhiB; r += 4) zpB += hls[r][c];
        }
        __syncthreads();
    }

    // ---- finalize z + q/k/v for both nodes ----
#pragma unroll
    for (int ni = 0; ni < 2; ni++) {
        float zp = ni ? zpB : zpA;
        int n = n0 + 2 * w + ni;
        zp += __shfl_xor(zp, 16);
        zp += __shfl_xor(zp, 32);
        if (lane < 16) z[n * 16 + lane] = zp;
        float aq = bq[lane], ak = bk[lane], av = bv[lane];
#pragma unroll
        for (int j = 0; j < 16; j++) {
            float zj = __shfl(zp, j, 16);
            aq = fmaf(Wq[lane * 16 + j], zj, aq);
            ak = fmaf(Wk[lane * 16 + j], zj, ak);
            av = fmaf(Wv[lane * 16 + j], zj, av);
        }
        q1[n * 64 + lane] = aq;
        k1[n * 64 + lane] = ak;
        v1[n * 64 + lane] = av;
    }
}

// ---------------- K_attn1: g1 attention at marked nodes, 4-edge unroll ----------------

__device__ __forceinline__ float red16(float t) {
    t += __shfl_xor(t, 1, 16);
    t += __shfl_xor(t, 2, 16);
    t += __shfl_xor(t, 4, 16);
    t += __shfl_xor(t, 8, 16);
    return t;
}

__global__ __launch_bounds__(256) void k_attn1(
    const float* __restrict__ ea,
    const float* __restrict__ q1, const float* __restrict__ k1, const float* __restrict__ v1,
    const float* __restrict__ We, const float* __restrict__ Ws, const float* __restrict__ bs,
    const float* __restrict__ z, const int* __restrict__ mark,
    const int* __restrict__ off, const int2* __restrict__ cpair,
    float* __restrict__ a1)
{
    int lane = threadIdx.x & 63;
    int wid  = threadIdx.x >> 6;
    int n    = (blockIdx.x & 7) * (NTOT / 8) + (blockIdx.x >> 3) * 4 + wid;

    if (!mark[n]) return;   // wave-uniform: a1[n] is never read

    float wer[8];
#pragma unroll
    for (int j = 0; j < 8; j++) wer[j] = We[lane * 8 + j];
    float ql = q1[n * 64 + lane];

    int o0 = off[n];
    int deg = off[n + 1] - o0;

    float m = -1e30f, l = 0.f, acc = 0.f;
    int i = 0;
    for (; i + 4 <= deg; i += 4) {
        int2 pA = cpair[o0 + i];
        int2 pB = cpair[o0 + i + 1];
        int2 pC = cpair[o0 + i + 2];
        int2 pD = cpair[o0 + i + 3];
        const float4* eaA = (const float4*)(ea + (size_t)pA.y * 8);
        const float4* eaB = (const float4*)(ea + (size_t)pB.y * 8);
        const float4* eaC = (const float4*)(ea + (size_t)pC.y * 8);
        const float4* eaD = (const float4*)(ea + (size_t)pD.y * 8);
        float4 a0 = eaA[0], a1v = eaA[1], b0 = eaB[0], b1v = eaB[1];
        float4 c0 = eaC[0], c1v = eaC[1], d0 = eaD[0], d1v = eaD[1];
        float eA = wer[0]*a0.x + wer[1]*a0.y + wer[2]*a0.z + wer[3]*a0.w
                 + wer[4]*a1v.x + wer[5]*a1v.y + wer[6]*a1v.z + wer[7]*a1v.w;
        float eB = wer[0]*b0.x + wer[1]*b0.y + wer[2]*b0.z + wer[3]*b0.w
                 + wer[4]*b1v.x + wer[5]*b1v.y + wer[6]*b1v.z + wer[7]*b1v.w;
        float eC = wer[0]*c0.x + wer[1]*c0.y + wer[2]*c0.z + wer[3]*c0.w
                 + wer[4]*c1v.x + wer[5]*c1v.y + wer[6]*c1v.z + wer[7]*c1v.w;
        float eD = wer[0]*d0.x + wer[1]*d0.y + wer[2]*d0.z + wer[3]*d0.w
                 + wer[4]*d1v.x + wer[5]*d1v.y + wer[6]*d1v.z + wer[7]*d1v.w;
        float kA = k1[(size_t)pA.x * 64 + lane];
        float kB = k1[(size_t)pB.x * 64 + lane];
        float kC = k1[(size_t)pC.x * 64 + lane];
        float kD = k1[(size_t)pD.x * 64 + lane];
        float vA = v1[(size_t)pA.x * 64 + lane];
        float vB = v1[(size_t)pB.x * 64 + lane];
        float vC = v1[(size_t)pC.x * 64 + lane];
        float vD = v1[(size_t)pD.x * 64 + lane];
        float lA = red16(ql * (kA + eA)) * 0.25f;
        float lB = red16(ql * (kB + eB)) * 0.25f;
        float lC = red16(ql * (kC + eC)) * 0.25f;
        float lD = red16(ql * (kD + eD)) * 0.25f;
        float nm = fmaxf(fmaxf(m, fmaxf(lA, lB)), fmaxf(lC, lD));
        float sc = __expf(m - nm);
        float wA = __expf(lA - nm);
        float wB = __expf(lB - nm);
        float wC = __expf(lC - nm);
        float wD = __expf(lD - nm);
        acc = acc * sc + wA * (vA + eA) + wB * (vB + eB) + wC * (vC + eC) + wD * (vD + eD);
        l   = l * sc + wA + wB + wC + wD;
        m   = nm;
    }
    for (; i < deg; i++) {
        int2 p = cpair[o0 + i];
        const float4* ea4 = (const float4*)(ea + (size_t)p.y * 8);
        float4 u0 = ea4[0], u1 = ea4[1];
        float el = wer[0]*u0.x + wer[1]*u0.y + wer[2]*u0.z + wer[3]*u0.w
                 + wer[4]*u1.x + wer[5]*u1.y + wer[6]*u1.z + wer[7]*u1.w;
        float kl = k1[(size_t)p.x * 64 + lane];
        float tq = red16(ql * (kl + el));
        float logit = tq * 0.25f;
        float nm = fmaxf(m, logit);
        float sc = __expf(m - nm);
        float wt = __expf(logit - nm);
        float vl = v1[(size_t)p.x * 64 + lane];
        acc = acc * sc + wt * (vl + el);
        l   = l * sc + wt;
        m   = nm;
    }
    float y = (deg > 0) ? (acc / l) : 0.f;
    y += __shfl_xor(y, 16);
    y += __shfl_xor(y, 32);
    y *= 0.25f;

    if (lane < 16) {
        float r = bs[lane];
#pragma unroll
        for (int j = 0; j < 16; j++) r = fmaf(Ws[lane * 16 + j], z[n * 16 + j], r);
        a1[n * 16 + lane] = y + r;
    }
}

// ---------------- K_g2: agent nodes only, 4 waves/batch + LDS merge ----------------

__global__ __launch_bounds__(256) void k_g2(
    const float* __restrict__ ea, const float* __restrict__ a1, const int* __restrict__ agent,
    const float* __restrict__ Wq, const float* __restrict__ bq,
    const float* __restrict__ Wk, const float* __restrict__ bk,
    const float* __restrict__ Wv, const float* __restrict__ bv,
    const float* __restrict__ We, const float* __restrict__ Ws, const float* __restrict__ bs,
    const int* __restrict__ off, const int2* __restrict__ cpair,
    float* __restrict__ out)
{
    __shared__ float sm[4][64], sl[4][64], sa0[4][64], sa1[4][64];
    int b = ((blockIdx.x & 7) << 4) + (blockIdx.x >> 3);
    int lane = threadIdx.x & 63;
    int w = threadIdx.x >> 6;
    int n = b * Nn + agent[b];
    int v0 = lane * 2, v1i = lane * 2 + 1;

    float aa[16];
#pragma unroll
    for (int j = 0; j < 16; j++) aa[j] = a1[n * 16 + j];

    float wk0[16], wk1[16], wv0[16], wv1[16], we0[8], we1[8];
#pragma unroll
    for (int j = 0; j < 16; j++) {
        wk0[j] = Wk[v0 * 16 + j];  wk1[j] = Wk[v1i * 16 + j];
        wv0[j] = Wv[v0 * 16 + j];  wv1[j] = Wv[v1i * 16 + j];
    }
#pragma unroll
    for (int j = 0; j < 8; j++) { we0[j] = We[v0 * 8 + j]; we1[j] = We[v1i * 8 + j]; }

    float q0 = bq[v0], q1v = bq[v1i];
#pragma unroll
    for (int j = 0; j < 16; j++) {
        q0  = fmaf(Wq[v0 * 16 + j],  aa[j], q0);
        q1v = fmaf(Wq[v1i * 16 + j], aa[j], q1v);
    }

    int o0 = off[n];
    int deg = off[n + 1] - o0;

    float m = -1e30f, l = 0.f, a0 = 0.f, a1c = 0.f;
    for (int i = w; i < deg; i += 4) {
        int2 p = cpair[o0 + i];
        int src = p.x, ge = p.y;
        float as[16];
#pragma unroll
        for (int j = 0; j < 16; j++) as[j] = a1[src * 16 + j];
        const float4* ea4 = (const float4*)(ea + (size_t)ge * 8);
        float4 u0 = ea4[0], u1 = ea4[1];
        float eav[8] = {u0.x, u0.y, u0.z, u0.w, u1.x, u1.y, u1.z, u1.w};

        float k0 = bk[v0], k1v = bk[v1i], vv0 = bv[v0], vv1 = bv[v1i];
#pragma unroll
        for (int j = 0; j < 16; j++) {
            k0  = fmaf(wk0[j], as[j], k0);
            k1v = fmaf(wk1[j], as[j], k1v);
            vv0 = fmaf(wv0[j], as[j], vv0);
            vv1 = fmaf(wv1[j], as[j], vv1);
        }
        float e0 = 0.f, e1 = 0.f;
#pragma unroll
        for (int j = 0; j < 8; j++) { e0 = fmaf(we0[j], eav[j], e0); e1 = fmaf(we1[j], eav[j], e1); }

        float t = q0 * (k0 + e0) + q1v * (k1v + e1);
        t += __shfl_xor(t, 1, 16);
        t += __shfl_xor(t, 2, 16);
        t += __shfl_xor(t, 4, 16);
        t += __shfl_xor(t, 8, 16);
        float logit = t * 0.17677669529663687f;  // / sqrt(32)
        float nm = fmaxf(m, logit);
        float sc = __expf(m - nm);
        float wgt = __expf(logit - nm);
        a0  = a0 * sc + wgt * (vv0 + e0);
        a1c = a1c * sc + wgt * (vv1 + e1);
        l   = l * sc + wgt;
        m   = nm;
    }
    sm[w][lane] = m; sl[w][lane] = l; sa0[w][lane] = a0; sa1[w][lane] = a1c;
    __syncthreads();
    if (w == 0) {
        float M = fmaxf(fmaxf(sm[0][lane], sm[1][lane]), fmaxf(sm[2][lane], sm[3][lane]));
        float L = 0.f, A0 = 0.f, A1 = 0.f;
#pragma unroll
        for (int ww = 0; ww < 4; ww++) {
            float sc = __expf(sm[ww][lane] - M);
            L  += sc * sl[ww][lane];
            A0 += sc * sa0[ww][lane];
            A1 += sc * sa1[ww][lane];
        }
        float y0 = (deg > 0) ? (A0 / L) : 0.f;
        float y1 = (deg > 0) ? (A1 / L) : 0.f;
        y0 += __shfl_xor(y0, 16); y0 += __shfl_xor(y0, 32);
        y1 += __shfl_xor(y1, 16); y1 += __shfl_xor(y1, 32);
        y0 *= 0.25f; y1 *= 0.25f;

        if (lane < 16) {
            int c0 = lane * 2, c1 = lane * 2 + 1;
            float r0 = bs[c0], r1 = bs[c1];
#pragma unroll
            for (int j = 0; j < 16; j++) {
                r0 = fmaf(Ws[c0 * 16 + j], aa[j], r0);
                r1 = fmaf(Ws[c1 * 16 + j], aa[j], r1);
            }
            out[b * 32 + c0] = fmaxf(y0 + r0, 0.f);
            out[b * 32 + c1] = fmaxf(y1 + r1, 0.f);
        }
    }
}

// ---------------- launch ----------------

extern "C" void kernel_launch(void* const* d_in, const int* in_sizes, int n_in,
                              void* d_out, int out_size, void* d_ws, size_t ws_size,
                              hipStream_t stream) {
    (void)in_sizes; (void)n_in; (void)out_size; (void)ws_size;
    const float* nf    = (const float*)d_in[0];
    const int*   ei    = (const int*)d_in[1];
    const float* ea    = (const float*)d_in[2];
    const int*   agent = (const int*)d_in[3];
    const float* ee    = (const float*)d_in[4];
    const float* W1    = (const float*)d_in[5];
    const float* b1    = (const float*)d_in[6];
    const float* W2    = (const float*)d_in[7];
    const float* b2    = (const float*)d_in[8];
    const float* W3    = (const float*)d_in[9];
    const float* b3    = (const float*)d_in[10];
    const float* lg    = (const float*)d_in[11];
    const float* lb    = (const float*)d_in[12];
    const float* g1Wq  = (const float*)d_in[13];
    const float* g1bq  = (const float*)d_in[14];
    const float* g1Wk  = (const float*)d_in[15];
    const float* g1bk  = (const float*)d_in[16];
    const float* g1Wv  = (const float*)d_in[17];
    const float* g1bv  = (const float*)d_in[18];
    const float* g1We  = (const float*)d_in[19];
    const float* g1Ws  = (const float*)d_in[20];
    const float* g1bs  = (const float*)d_in[21];
    const float* g2Wq  = (const float*)d_in[22];
    const float* g2bq  = (const float*)d_in[23];
    const float* g2Wk  = (const float*)d_in[24];
    const float* g2bk  = (const float*)d_in[25];
    const float* g2Wv  = (const float*)d_in[26];
    const float* g2bv  = (const float*)d_in[27];
    const float* g2We  = (const float*)d_in[28];
    const float* g2Ws  = (const float*)d_in[29];
    const float* g2bs  = (const float*)d_in[30];
    float* out = (float*)d_out;

    char* w = (char*)d_ws;
    int* mark  = (int*)w;  w += (size_t)NTOT * 4;
    int* off   = (int*)w;  w += (size_t)(NTOT + 4) * 4;
    w = (char*)(((uintptr_t)w + 15) & ~(uintptr_t)15);
    int2* cpair = (int2*)w; w += (size_t)ETOT * 8;
    float* z   = (float*)w; w += (size_t)NTOT * 16 * 4;
    float* q1  = (float*)w; w += (size_t)NTOT * 64 * 4;
    float* k1  = (float*)w; w += (size_t)NTOT * 64 * 4;
    float* v1  = (float*)w; w += (size_t)NTOT * 64 * 4;
    float* a1  = (float*)w; w += (size_t)NTOT * 16 * 4;

    k_csr<<<dim3(Bb), dim3(256), 0, stream>>>(ei, agent, off, cpair, mark);
    k_mlpz<<<dim3(NTOT / 16), dim3(512), 0, stream>>>(
        nf, ea, ee, W1, b1, W2, b2, W3, b3, lg, lb,
        g1Wq, g1bq, g1Wk, g1bk, g1Wv, g1bv,
        off, cpair, z, q1, k1, v1);
    k_attn1<<<dim3(NTOT / 4), dim3(256), 0, stream>>>(
        ea, q1, k1, v1, g1We, g1Ws, g1bs, z, mark, off, cpair, a1);
    k_g2<<<dim3(Bb), dim3(256), 0, stream>>>(
        ea, a1, agent, g2Wq, g2bq, g2Wk, g2bk, g2Wv, g2bv, g2We, g2Ws, g2bs,
        off, cpair, out);
}

// Round 7
// 205.605 us; speedup vs baseline: 2.1562x; 2.1562x over previous
//
#include <hip/hip_runtime.h>
#include <math.h>
#include <stdint.h>

#define Bb   128
#define Nn   100
#define Ee   3200
#define NTOT (Bb*Nn)    // 12800
#define ETOT (Bb*Ee)    // 409600

// XCD swizzle: blockIdx&7 -> XCD (dispatch round-robin over 8 XCDs).
// XCD x owns batches [16x,16x+16): producers and consumers of a batch's
// data land on the same XCD -> L2-resident intermediates. Perf-only.
// R5/R6 lessons (both measured): one-block-per-batch mega-fusion = 8-21%
// occupancy, 313-330us (latency-bound, nothing to hide behind); big-LDS
// edge-parallel MLP = same failure. This 4-kernel / 256-thread / small-LDS
// shape is the empirical optimum (205us at R4). Do not re-fuse.

// ---------------- K_csr: per-batch CSR build + mark, all-LDS ----------------

__global__ __launch_bounds__(256) void k_csr(const int* __restrict__ ei,
                                             const int* __restrict__ agent,
                                             int* __restrict__ off,
                                             int2* __restrict__ cpair,
                                             int* __restrict__ mark)
{
    int b = ((blockIdx.x & 7) << 4) + (blockIdx.x >> 3);
    int t = threadIdx.x;
    __shared__ int cnt[128];
    __shared__ int exc[128];
    __shared__ int cur[128];
    if (t < 128) cnt[t] = 0;
    if (t < Nn) mark[b * Nn + t] = 0;
    __syncthreads();
    const int* eis = ei + (size_t)b * 2 * Ee;       // src row
    const int* eid = eis + Ee;                      // dst row
    for (int e = t; e < Ee; e += 256) atomicAdd(&cnt[eid[e]], 1);
    __syncthreads();
    if (t < 128) exc[t] = cnt[t];
    __syncthreads();
    for (int d = 1; d < 128; d <<= 1) {
        int v = 0;
        if (t < 128 && t >= d) v = exc[t - d];
        __syncthreads();
        if (t < 128) exc[t] += v;
        __syncthreads();
    }
    if (t < 128) { int e0 = exc[t] - cnt[t]; exc[t] = e0; cur[t] = e0; }  // exclusive
    __syncthreads();
    if (t < Nn) off[b * Nn + t] = b * Ee + exc[t];
    if (b == Bb - 1 && t == 0) off[NTOT] = ETOT;
    int an = agent[b];
    for (int e = t; e < Ee; e += 256) {
        int dst = eid[e];
        int idx = atomicAdd(&cur[dst], 1);
        cpair[(size_t)b * Ee + idx] = make_int2(eis[e] + b * Nn, b * Ee + e);
        if (dst == an) mark[b * Nn + eis[e]] = 1;
    }
    if (t == 0) mark[b * Nn + an] = 1;
}

// ---------------- K_mlpz: fused edge-MLP + node-sum + q/k/v ----------------
// one wave per node; thread-owns-edge MLP in regs; LDS[64][17] transpose
// (R4-proven: ran below the 42us profile floor)

__device__ __forceinline__ void ln_reg(float* h, const float* __restrict__ g,
                                       const float* __restrict__ b) {
    float s = 0.f;
#pragma unroll
    for (int c = 0; c < 16; c++) s += h[c];
    float m = s * 0.0625f;
    float v = 0.f;
#pragma unroll
    for (int c = 0; c < 16; c++) { float d = h[c] - m; v += d * d; }
    float r = rsqrtf(v * 0.0625f + 1e-5f);
#pragma unroll
    for (int c = 0; c < 16; c++) h[c] = (h[c] - m) * r * g[c] + b[c];
}

__global__ __launch_bounds__(256) void k_mlpz(
    const float* __restrict__ nf, const float* __restrict__ ea, const float* __restrict__ ee,
    const float* __restrict__ W1, const float* __restrict__ b1,
    const float* __restrict__ W2, const float* __restrict__ b2,
    const float* __restrict__ W3, const float* __restrict__ b3,
    const float* __restrict__ lg, const float* __restrict__ lb,
    const float* __restrict__ Wq, const float* __restrict__ bq,
    const float* __restrict__ Wk, const float* __restrict__ bk,
    const float* __restrict__ Wv, const float* __restrict__ bv,
    const int* __restrict__ off, const int2* __restrict__ cpair,
    float* __restrict__ z, float* __restrict__ q1, float* __restrict__ k1, float* __restrict__ v1)
{
    __shared__ float hs[4][64][17];   // stride 17: 2 lanes/bank on write & read = free
    __shared__ int sdeg[4];
    int lane = threadIdx.x & 63;
    int wid  = threadIdx.x >> 6;
    int n    = (blockIdx.x & 7) * (NTOT / 8) + (blockIdx.x >> 3) * 4 + wid;

    int o0 = off[n];
    int deg = off[n + 1] - o0;
    if (lane == 0) sdeg[wid] = deg;
    __syncthreads();
    int mdeg = max(max(sdeg[0], sdeg[1]), max(sdeg[2], sdeg[3]));
    int chunks = (mdeg + 63) >> 6;

    float zp = 0.f;
    for (int ch = 0; ch < chunks; ch++) {
        int i = ch * 64 + lane;
        float h3[16];
        if (i < deg) {
            int2 p = cpair[o0 + i];
            int et = (int)nf[p.x];
            float in[12];
#pragma unroll
            for (int j = 0; j < 4; j++) in[j] = ee[et * 4 + j];
            const float4* ea4 = (const float4*)(ea + (size_t)p.y * 8);
            float4 ua = ea4[0], ub = ea4[1];
            in[4] = ua.x; in[5] = ua.y; in[6] = ua.z; in[7] = ua.w;
            in[8] = ub.x; in[9] = ub.y; in[10] = ub.z; in[11] = ub.w;

            float h1[16];
#pragma unroll
            for (int c = 0; c < 16; c++) {
                float s = b1[c];
#pragma unroll
                for (int j = 0; j < 12; j++) s = fmaf(W1[c * 12 + j], in[j], s);
                h1[c] = fmaxf(s, 0.f);
            }
            ln_reg(h1, lg, lb);
            float h2[16];
#pragma unroll
            for (int c = 0; c < 16; c++) {
                float s = b2[c];
#pragma unroll
                for (int j = 0; j < 16; j++) s = fmaf(W2[c * 16 + j], h1[j], s);
                h2[c] = fmaxf(s, 0.f);
            }
            ln_reg(h2, lg, lb);
#pragma unroll
            for (int c = 0; c < 16; c++) {
                float s = b3[c];
#pragma unroll
                for (int j = 0; j < 16; j++) s = fmaf(W3[c * 16 + j], h2[j], s);
                h3[c] = fmaxf(s, 0.f);
            }
            ln_reg(h3, lg, lb);
        } else {
#pragma unroll
            for (int c = 0; c < 16; c++) h3[c] = 0.f;
        }
#pragma unroll
        for (int c = 0; c < 16; c++) hs[wid][lane][c] = h3[c];
        __syncthreads();
        int g = lane >> 4, c = lane & 15;
        float s = 0.f;
#pragma unroll
        for (int k = 0; k < 16; k++) s += hs[wid][g * 16 + k][c];
        s += __shfl_xor(s, 16);
        s += __shfl_xor(s, 32);
        zp += s;
        __syncthreads();
    }

    if (lane < 16) z[n * 16 + lane] = zp;

    float aq = bq[lane], ak = bk[lane], av = bv[lane];
#pragma unroll
    for (int j = 0; j < 16; j++) {
        float zj = __shfl(zp, j, 16);
        aq = fmaf(Wq[lane * 16 + j], zj, aq);
        ak = fmaf(Wk[lane * 16 + j], zj, ak);
        av = fmaf(Wv[lane * 16 + j], zj, av);
    }
    q1[n * 64 + lane] = aq;
    k1[n * 64 + lane] = ak;
    v1[n * 64 + lane] = av;
}

// ---------------- K_attn1: g1 attention at marked nodes only (R4-proven) ----------------

__global__ __launch_bounds__(256) void k_attn1(
    const float* __restrict__ ea,
    const float* __restrict__ q1, const float* __restrict__ k1, const float* __restrict__ v1,
    const float* __restrict__ We, const float* __restrict__ Ws, const float* __restrict__ bs,
    const float* __restrict__ z, const int* __restrict__ mark,
    const int* __restrict__ off, const int2* __restrict__ cpair,
    float* __restrict__ a1)
{
    int lane = threadIdx.x & 63;
    int wid  = threadIdx.x >> 6;
    int n    = (blockIdx.x & 7) * (NTOT / 8) + (blockIdx.x >> 3) * 4 + wid;

    if (!mark[n]) return;   // wave-uniform: a1[n] is never read

    float wer[8];
#pragma unroll
    for (int j = 0; j < 8; j++) wer[j] = We[lane * 8 + j];
    float ql = q1[n * 64 + lane];

    int o0 = off[n];
    int deg = off[n + 1] - o0;

    float m = -1e30f, l = 0.f, acc = 0.f;
    int i = 0;
    for (; i + 2 <= deg; i += 2) {
        int2 pA = cpair[o0 + i];
        int2 pB = cpair[o0 + i + 1];
        const float4* eaA = (const float4*)(ea + (size_t)pA.y * 8);
        const float4* eaB = (const float4*)(ea + (size_t)pB.y * 8);
        float4 a0v = eaA[0], a1v = eaA[1], b0v = eaB[0], b1v = eaB[1];
        float eA = wer[0] * a0v.x + wer[1] * a0v.y + wer[2] * a0v.z + wer[3] * a0v.w
                 + wer[4] * a1v.x + wer[5] * a1v.y + wer[6] * a1v.z + wer[7] * a1v.w;
        float eB = wer[0] * b0v.x + wer[1] * b0v.y + wer[2] * b0v.z + wer[3] * b0v.w
                 + wer[4] * b1v.x + wer[5] * b1v.y + wer[6] * b1v.z + wer[7] * b1v.w;
        float kA = k1[(size_t)pA.x * 64 + lane];
        float kB = k1[(size_t)pB.x * 64 + lane];
        float vA = v1[(size_t)pA.x * 64 + lane];
        float vB = v1[(size_t)pB.x * 64 + lane];
        float tA = ql * (kA + eA);
        float tB = ql * (kB + eB);
        tA += __shfl_xor(tA, 1, 16);  tB += __shfl_xor(tB, 1, 16);
        tA += __shfl_xor(tA, 2, 16);  tB += __shfl_xor(tB, 2, 16);
        tA += __shfl_xor(tA, 4, 16);  tB += __shfl_xor(tB, 4, 16);
        tA += __shfl_xor(tA, 8, 16);  tB += __shfl_xor(tB, 8, 16);
        float lA = tA * 0.25f;
        float lB = tB * 0.25f;
        float nm = fmaxf(m, fmaxf(lA, lB));
        float sc = __expf(m - nm);
        float wA = __expf(lA - nm);
        float wB = __expf(lB - nm);
        acc = acc * sc + wA * (vA + eA) + wB * (vB + eB);
        l   = l * sc + wA + wB;
        m   = nm;
    }
    for (; i < deg; i++) {
        int2 p = cpair[o0 + i];
        const float4* ea4 = (const float4*)(ea + (size_t)p.y * 8);
        float4 u0 = ea4[0], u1 = ea4[1];
        float el = wer[0] * u0.x + wer[1] * u0.y + wer[2] * u0.z + wer[3] * u0.w
                 + wer[4] * u1.x + wer[5] * u1.y + wer[6] * u1.z + wer[7] * u1.w;
        float kl = k1[(size_t)p.x * 64 + lane];
        float t = ql * (kl + el);
        t += __shfl_xor(t, 1, 16);
        t += __shfl_xor(t, 2, 16);
        t += __shfl_xor(t, 4, 16);
        t += __shfl_xor(t, 8, 16);
        float logit = t * 0.25f;
        float nm = fmaxf(m, logit);
        float sc = __expf(m - nm);
        float w  = __expf(logit - nm);
        float vl = v1[(size_t)p.x * 64 + lane];
        acc = acc * sc + w * (vl + el);
        l   = l * sc + w;
        m   = nm;
    }
    float y = (deg > 0) ? (acc / l) : 0.f;
    y += __shfl_xor(y, 16);
    y += __shfl_xor(y, 32);
    y *= 0.25f;

    if (lane < 16) {
        float r = bs[lane];
#pragma unroll
        for (int j = 0; j < 16; j++) r = fmaf(Ws[lane * 16 + j], z[n * 16 + j], r);
        a1[n * 16 + lane] = y + r;
    }
}

// ---------------- K_g2: agent nodes only, 8 waves/batch + LDS merge ----------------
// (only delta vs R4: 4 -> 8 waves, halves the serial online-softmax chain)

__global__ __launch_bounds__(512) void k_g2(
    const float* __restrict__ ea, const float* __restrict__ a1, const int* __restrict__ agent,
    const float* __restrict__ Wq, const float* __restrict__ bq,
    const float* __restrict__ Wk, const float* __restrict__ bk,
    const float* __restrict__ Wv, const float* __restrict__ bv,
    const float* __restrict__ We, const float* __restrict__ Ws, const float* __restrict__ bs,
    const int* __restrict__ off, const int2* __restrict__ cpair,
    float* __restrict__ out)
{
    __shared__ float sm[8][64], sl[8][64], sa0[8][64], sa1[8][64];
    int b = ((blockIdx.x & 7) << 4) + (blockIdx.x >> 3);
    int lane = threadIdx.x & 63;
    int w = threadIdx.x >> 6;
    int n = b * Nn + agent[b];
    int v0 = lane * 2, v1i = lane * 2 + 1;

    float aa[16];
#pragma unroll
    for (int j = 0; j < 16; j++) aa[j] = a1[n * 16 + j];

    float wk0[16], wk1[16], wv0[16], wv1[16], we0[8], we1[8];
#pragma unroll
    for (int j = 0; j < 16; j++) {
        wk0[j] = Wk[v0 * 16 + j];  wk1[j] = Wk[v1i * 16 + j];
        wv0[j] = Wv[v0 * 16 + j];  wv1[j] = Wv[v1i * 16 + j];
    }
#pragma unroll
    for (int j = 0; j < 8; j++) { we0[j] = We[v0 * 8 + j]; we1[j] = We[v1i * 8 + j]; }

    float q0 = bq[v0], q1v = bq[v1i];
#pragma unroll
    for (int j = 0; j < 16; j++) {
        q0  = fmaf(Wq[v0 * 16 + j],  aa[j], q0);
        q1v = fmaf(Wq[v1i * 16 + j], aa[j], q1v);
    }

    int o0 = off[n];
    int deg = off[n + 1] - o0;

    float m = -1e30f, l = 0.f, a0 = 0.f, a1c = 0.f;
    for (int i = w; i < deg; i += 8) {
        int2 p = cpair[o0 + i];
        int src = p.x, ge = p.y;
        float as[16];
#pragma unroll
        for (int j = 0; j < 16; j++) as[j] = a1[src * 16 + j];
        const float4* ea4 = (const float4*)(ea + (size_t)ge * 8);
        float4 u0 = ea4[0], u1 = ea4[1];
        float eav[8] = {u0.x, u0.y, u0.z, u0.w, u1.x, u1.y, u1.z, u1.w};

        float k0 = bk[v0], k1v = bk[v1i], vv0 = bv[v0], vv1 = bv[v1i];
#pragma unroll
        for (int j = 0; j < 16; j++) {
            k0  = fmaf(wk0[j], as[j], k0);
            k1v = fmaf(wk1[j], as[j], k1v);
            vv0 = fmaf(wv0[j], as[j], vv0);
            vv1 = fmaf(wv1[j], as[j], vv1);
        }
        float e0 = 0.f, e1 = 0.f;
#pragma unroll
        for (int j = 0; j < 8; j++) { e0 = fmaf(we0[j], eav[j], e0); e1 = fmaf(we1[j], eav[j], e1); }

        float t = q0 * (k0 + e0) + q1v * (k1v + e1);
        t += __shfl_xor(t, 1, 16);
        t += __shfl_xor(t, 2, 16);
        t += __shfl_xor(t, 4, 16);
        t += __shfl_xor(t, 8, 16);
        float logit = t * 0.17677669529663687f;  // / sqrt(32)
        float nm = fmaxf(m, logit);
        float sc = __expf(m - nm);
        float wgt = __expf(logit - nm);
        a0  = a0 * sc + wgt * (vv0 + e0);
        a1c = a1c * sc + wgt * (vv1 + e1);
        l   = l * sc + wgt;
        m   = nm;
    }
    sm[w][lane] = m; sl[w][lane] = l; sa0[w][lane] = a0; sa1[w][lane] = a1c;
    __syncthreads();
    if (w == 0) {
        float M = sm[0][lane];
#pragma unroll
        for (int ww = 1; ww < 8; ww++) M = fmaxf(M, sm[ww][lane]);
        float L = 0.f, A0 = 0.f, A1 = 0.f;
#pragma unroll
        for (int ww = 0; ww < 8; ww++) {
            float sc = __expf(sm[ww][lane] - M);
            L  += sc * sl[ww][lane];
            A0 += sc * sa0[ww][lane];
            A1 += sc * sa1[ww][lane];
        }
        float y0 = (deg > 0) ? (A0 / L) : 0.f;
        float y1 = (deg > 0) ? (A1 / L) : 0.f;
        y0 += __shfl_xor(y0, 16); y0 += __shfl_xor(y0, 32);
        y1 += __shfl_xor(y1, 16); y1 += __shfl_xor(y1, 32);
        y0 *= 0.25f; y1 *= 0.25f;

        if (lane < 16) {
            int c0 = lane * 2, c1 = lane * 2 + 1;
            float r0 = bs[c0], r1 = bs[c1];
#pragma unroll
            for (int j = 0; j < 16; j++) {
                r0 = fmaf(Ws[c0 * 16 + j], aa[j], r0);
                r1 = fmaf(Ws[c1 * 16 + j], aa[j], r1);
            }
            out[b * 32 + c0] = fmaxf(y0 + r0, 0.f);
            out[b * 32 + c1] = fmaxf(y1 + r1, 0.f);
        }
    }
}

// ---------------- launch ----------------

extern "C" void kernel_launch(void* const* d_in, const int* in_sizes, int n_in,
                              void* d_out, int out_size, void* d_ws, size_t ws_size,
                              hipStream_t stream) {
    (void)in_sizes; (void)n_in; (void)out_size; (void)ws_size;
    const float* nf    = (const float*)d_in[0];
    const int*   ei    = (const int*)d_in[1];
    const float* ea    = (const float*)d_in[2];
    const int*   agent = (const int*)d_in[3];
    const float* ee    = (const float*)d_in[4];
    const float* W1    = (const float*)d_in[5];
    const float* b1    = (const float*)d_in[6];
    const float* W2    = (const float*)d_in[7];
    const float* b2    = (const float*)d_in[8];
    const float* W3    = (const float*)d_in[9];
    const float* b3    = (const float*)d_in[10];
    const float* lg    = (const float*)d_in[11];
    const float* lb    = (const float*)d_in[12];
    const float* g1Wq  = (const float*)d_in[13];
    const float* g1bq  = (const float*)d_in[14];
    const float* g1Wk  = (const float*)d_in[15];
    const float* g1bk  = (const float*)d_in[16];
    const float* g1Wv  = (const float*)d_in[17];
    const float* g1bv  = (const float*)d_in[18];
    const float* g1We  = (const float*)d_in[19];
    const float* g1Ws  = (const float*)d_in[20];
    const float* g1bs  = (const float*)d_in[21];
    const float* g2Wq  = (const float*)d_in[22];
    const float* g2bq  = (const float*)d_in[23];
    const float* g2Wk  = (const float*)d_in[24];
    const float* g2bk  = (const float*)d_in[25];
    const float* g2Wv  = (const float*)d_in[26];
    const float* g2bv  = (const float*)d_in[27];
    const float* g2We  = (const float*)d_in[28];
    const float* g2Ws  = (const float*)d_in[29];
    const float* g2bs  = (const float*)d_in[30];
    float* out = (float*)d_out;

    char* w = (char*)d_ws;
    int* mark  = (int*)w;  w += (size_t)NTOT * 4;
    int* off   = (int*)w;  w += (size_t)(NTOT + 4) * 4;
    w = (char*)(((uintptr_t)w + 15) & ~(uintptr_t)15);
    int2* cpair = (int2*)w; w += (size_t)ETOT * 8;
    float* z   = (float*)w; w += (size_t)NTOT * 16 * 4;
    float* q1  = (float*)w; w += (size_t)NTOT * 64 * 4;
    float* k1  = (float*)w; w += (size_t)NTOT * 64 * 4;
    float* v1  = (float*)w; w += (size_t)NTOT * 64 * 4;
    float* a1  = (float*)w; w += (size_t)NTOT * 16 * 4;

    k_csr<<<dim3(Bb), dim3(256), 0, stream>>>(ei, agent, off, cpair, mark);
    k_mlpz<<<dim3(NTOT / 4), dim3(256), 0, stream>>>(
        nf, ea, ee, W1, b1, W2, b2, W3, b3, lg, lb,
        g1Wq, g1bq, g1Wk, g1bk, g1Wv, g1bv,
        off, cpair, z, q1, k1, v1);
    k_attn1<<<dim3(NTOT / 4), dim3(256), 0, stream>>>(
        ea, q1, k1, v1, g1We, g1Ws, g1bs, z, mark, off, cpair, a1);
    k_g2<<<dim3(Bb), dim3(512), 0, stream>>>(
        ea, a1, agent, g2Wq, g2bq, g2Wk, g2bk, g2Wv, g2bv, g2We, g2Ws, g2bs,
        off, cpair, out);
}